// Round 3
// baseline (1187.976 us; speedup 1.0000x reference)
//
#include <hip/hip_runtime.h>
#include <stdint.h>

#define NODES   100000
#define NPAD    100096   // 782 * 128 = 391 * 256 = 1564 * 64
#define DIM     512
#define NPAIR   2048
#define MROWS   4096     // 2048 l-rows + 2048 r-rows
#define NB      782      // NPAD / TN
#define MPAGES  32       // MROWS / 128
#define GAMMA_F 3.0f
#define LAMB_F  20.0f
#define TAU_F   8.0f
#define SHIFT_F 140.0f   // LAMB * 7 (7-sigma LSE shift)

#define TM 128
#define TN 128
#define BK 64

typedef __attribute__((ext_vector_type(8))) short          short8;
typedef __attribute__((ext_vector_type(8))) unsigned short ushort8;
typedef __attribute__((ext_vector_type(4))) unsigned short ushort4v;
typedef __attribute__((ext_vector_type(4))) float          f32x4;

// ---- helpers -------------------------------------------------------------

__device__ __forceinline__ unsigned short f2bf(float f) {
    unsigned u = __float_as_uint(f);
    u += 0x7FFFu + ((u >> 16) & 1u);   // RNE
    return (unsigned short)(u >> 16);
}
__device__ __forceinline__ float bf2f(unsigned short h) {
    return __uint_as_float(((unsigned)h) << 16);
}

// async global->LDS, 16B per lane; lds dest = wave-uniform base + lane*16
__device__ __forceinline__ void gload_lds16(const void* g, void* l) {
    unsigned lofs = (unsigned)__builtin_amdgcn_readfirstlane((unsigned)(uintptr_t)l);
    auto lp = reinterpret_cast<__attribute__((address_space(3))) unsigned*>(lofs);
    auto gp = (const __attribute__((address_space(1))) unsigned*)g;
    __builtin_amdgcn_global_load_lds(gp, lp, 16, 0, 0);
}

// ---- fused convert + stats partials --------------------------------------

__global__ void convert_stats_kernel(const float* __restrict__ emb,
                                     unsigned short* __restrict__ Ebf,
                                     float* __restrict__ esq,
                                     float* __restrict__ Spart,
                                     float* __restrict__ Tpart,
                                     float* __restrict__ E1part,
                                     float* __restrict__ E2part) {
    __shared__ float Sl[4][512];
    __shared__ float Tl[4][512];
    __shared__ float ew[8];
    const int b = blockIdx.x, t = threadIdx.x;
    const int lane = t & 63, wave = t >> 6;
    const int r0 = b * 196;
    float sacc[8], tacc[8];
    #pragma unroll
    for (int k = 0; k < 8; ++k) { sacc[k] = 0.f; tacc[k] = 0.f; }
    float e1 = 0.f, e2 = 0.f;
    for (int i = 0; i < 49; ++i) {
        const int row = r0 + i * 4 + wave;
        if (row >= NPAD) continue;
        const bool real = row < NODES;
        float v[8];
        float ss = 0.f;
        if (real) {
            const float4* p = (const float4*)(emb + (size_t)row * DIM + lane * 8);
            float4 a = p[0], bb = p[1];
            v[0]=a.x; v[1]=a.y; v[2]=a.z; v[3]=a.w;
            v[4]=bb.x; v[5]=bb.y; v[6]=bb.z; v[7]=bb.w;
            #pragma unroll
            for (int k = 0; k < 8; ++k) ss += v[k] * v[k];
        } else {
            #pragma unroll
            for (int k = 0; k < 8; ++k) v[k] = 0.f;
        }
        #pragma unroll
        for (int o = 1; o < 64; o <<= 1) ss += __shfl_xor(ss, o);
        ushort8 o8;
        float vr[8];
        #pragma unroll
        for (int k = 0; k < 8; ++k) { o8[k] = f2bf(v[k]); vr[k] = bf2f(o8[k]); }
        *(ushort8*)(Ebf + (size_t)row * DIM + lane * 8) = o8;
        if (lane == 0) esq[row] = ss;
        if (real) {
            #pragma unroll
            for (int k = 0; k < 8; ++k) { sacc[k] += vr[k]; tacc[k] += ss * vr[k]; }
            if (lane == 0) { e1 += ss; e2 += ss * ss; }
        }
    }
    #pragma unroll
    for (int k = 0; k < 8; ++k) {
        Sl[wave][lane * 8 + k] = sacc[k];
        Tl[wave][lane * 8 + k] = tacc[k];
    }
    if (lane == 0) { ew[wave] = e1; ew[4 + wave] = e2; }
    __syncthreads();
    #pragma unroll
    for (int kk = 0; kk < 2; ++kk) {
        const int d = 2 * t + kk;
        Spart[(size_t)b * 512 + d] = Sl[0][d] + Sl[1][d] + Sl[2][d] + Sl[3][d];
        Tpart[(size_t)b * 512 + d] = Tl[0][d] + Tl[1][d] + Tl[2][d] + Tl[3][d];
    }
    if (t == 0) E1part[b] = ew[0] + ew[1] + ew[2] + ew[3];
    if (t == 1) E2part[b] = ew[4] + ew[5] + ew[6] + ew[7];
}

__global__ void stats_merge_kernel(const float* __restrict__ Spart,
                                   const float* __restrict__ Tpart,
                                   const float* __restrict__ E1part,
                                   const float* __restrict__ E2part,
                                   float* __restrict__ Svec,
                                   float* __restrict__ Tvec,
                                   double* __restrict__ E12) {
    const int t = threadIdx.x;   // 1024 threads
    if (t < 512) {
        float s = 0.f;
        for (int b = 0; b < 512; ++b) s += Spart[(size_t)b * 512 + t];
        Svec[t] = s;
    } else {
        const int d = t - 512;
        float s = 0.f;
        for (int b = 0; b < 512; ++b) s += Tpart[(size_t)b * 512 + d];
        Tvec[d] = s;
    }
    if (t == 0) { double a = 0.0; for (int b = 0; b < 512; ++b) a += (double)E1part[b]; E12[0] = a; }
    if (t == 1) { double a = 0.0; for (int b = 0; b < 512; ++b) a += (double)E2part[b]; E12[1] = a; }
}

// gather A rows (bf16) + c[m] = pos - |a|^2 + gamma ; posv[p] = pos
__global__ void gather_kernel(const int* __restrict__ pairs,
                              const float* __restrict__ emb,
                              unsigned short* __restrict__ Abf,
                              float* __restrict__ cvec,
                              float* __restrict__ posv) {
    const int p    = blockIdx.x;
    const int lane = threadIdx.x;
    const int li = pairs[2 * p], ri = pairs[2 * p + 1];
    const float4* pl = (const float4*)(emb + (size_t)li * DIM + lane * 8);
    const float4* pr = (const float4*)(emb + (size_t)ri * DIM + lane * 8);
    float4 a0 = pl[0], a1 = pl[1];
    float4 b0 = pr[0], b1 = pr[1];
    float la[8] = {a0.x,a0.y,a0.z,a0.w,a1.x,a1.y,a1.z,a1.w};
    float lb[8] = {b0.x,b0.y,b0.z,b0.w,b1.x,b1.y,b1.z,b1.w};
    float sa = 0.f, sb = 0.f, sd = 0.f;
    ushort8 oa, ob;
    #pragma unroll
    for (int i = 0; i < 8; ++i) {
        sa += la[i] * la[i];
        sb += lb[i] * lb[i];
        float d = la[i] - lb[i];
        sd += d * d;
        oa[i] = f2bf(la[i]);
        ob[i] = f2bf(lb[i]);
    }
    *(ushort8*)(Abf + (size_t)p * DIM + lane * 8)            = oa;
    *(ushort8*)(Abf + (size_t)(NPAIR + p) * DIM + lane * 8)  = ob;
    #pragma unroll
    for (int off = 1; off < 64; off <<= 1) {
        sa += __shfl_xor(sa, off);
        sb += __shfl_xor(sb, off);
        sd += __shfl_xor(sd, off);
    }
    if (lane == 0) {
        cvec[p]         = sd - sa + GAMMA_F;
        cvec[NPAIR + p] = sd - sb + GAMMA_F;
        posv[p]         = sd;
    }
}

// ---- transpose: Ebf [j][d] -> EbfT [d][j] --------------------------------
// Tile 256 j x 64 d. LDS [64][257] u16 (pad 1 -> write banks 2-way, free).
// Phase 1: coalesced ushort8 row reads, scalar transposed LDS writes.
// Phase 2: contiguous-j ushort4 global writes (512 B per wave).

__global__ void transpose_kernel(const unsigned short* __restrict__ Ebf,
                                 unsigned short* __restrict__ EbfT) {
    __shared__ unsigned short tl[64][257];
    const int t  = threadIdx.x;            // 256
    const int j0 = blockIdx.x * 256;
    const int d0 = blockIdx.y * 64;
    const int c  = t & 7;                  // d-chunk
    const int rr = t >> 3;                 // j-row within 32-group
    #pragma unroll
    for (int it = 0; it < 8; ++it) {
        const int r = it * 32 + rr;
        ushort8 v = *(const ushort8*)(Ebf + (size_t)(j0 + r) * DIM + d0 + c * 8);
        #pragma unroll
        for (int i = 0; i < 8; ++i)
            tl[c * 8 + i][r] = v[i];
    }
    __syncthreads();
    const int lane = t & 63, wave = t >> 6;
    #pragma unroll
    for (int it = 0; it < 16; ++it) {
        const int dd = it * 4 + wave;
        ushort4v o;
        #pragma unroll
        for (int i = 0; i < 4; ++i) o[i] = tl[dd][lane * 4 + i];
        *(ushort4v*)(EbfT + (size_t)(d0 + dd) * NPAD + j0 + lane * 4) = o;
    }
}

// ---- Gram GEMM v2: Gpart[bz] = partial E^T E via EbfT --------------------
// Clone of the main 128x128 gemm structure: contraction axis (j) is the
// contiguous axis of EbfT, so staging uses gload_lds16 + XOR swizzle and
// fragment reads are ds_read_b128 (was: 128 scalar ds_read_u16 per lane).

__launch_bounds__(256, 2)
__global__ void gram_kernel(const unsigned short* __restrict__ EbfT,
                            float* __restrict__ Gpart) {
    __shared__ unsigned short ldsA[TM * BK];  // 16 KB  (rows = d1, cols = j)
    __shared__ unsigned short ldsB[TM * BK];  // 16 KB  (rows = d2, cols = j)
    const int tid  = threadIdx.x;
    const int lane = tid & 63;
    const int wave = tid >> 6;
    const int wx = wave & 1, wy = wave >> 1;
    const int d1base = blockIdx.y * 128;
    const int d2base = blockIdx.x * 128;
    const int bz = blockIdx.z;
    const int r15 = lane & 15, q = lane >> 4;
    const int lrow   = lane >> 3;
    const int lchunk = lane & 7;

    f32x4 zero4 = {0.f, 0.f, 0.f, 0.f};
    f32x4 acc[4][4];
    #pragma unroll
    for (int i = 0; i < 4; ++i)
        #pragma unroll
        for (int j = 0; j < 4; ++j) acc[i][j] = zero4;

    for (int jc = bz; jc < NPAD / 64; jc += 32) {
        const int j0 = jc * 64;
        #pragma unroll
        for (int jj = 0; jj < 4; ++jj) {
            const int rbase = (wave * 4 + jj) * 8;
            const int row   = rbase + lrow;
            const int gch   = lchunk ^ (row & 7);
            gload_lds16(EbfT + ((size_t)(d1base + row) * NPAD + j0 + gch * 8),
                        &ldsA[rbase * BK]);
            gload_lds16(EbfT + ((size_t)(d2base + row) * NPAD + j0 + gch * 8),
                        &ldsB[rbase * BK]);
        }
        __builtin_amdgcn_s_waitcnt(0);
        __syncthreads();
        #pragma unroll
        for (int h = 0; h < 2; ++h) {
            short8 af[4], bfv[4];
            #pragma unroll
            for (int mt = 0; mt < 4; ++mt) {
                const int row = wy * 64 + mt * 16 + r15;
                const int cc  = (h * 4 + q) ^ (row & 7);
                af[mt] = *(const short8*)&ldsA[row * BK + cc * 8];
            }
            #pragma unroll
            for (int nt = 0; nt < 4; ++nt) {
                const int row = wx * 64 + nt * 16 + r15;
                const int cc  = (h * 4 + q) ^ (row & 7);
                bfv[nt] = *(const short8*)&ldsB[row * BK + cc * 8];
            }
            #pragma unroll
            for (int mt = 0; mt < 4; ++mt)
                #pragma unroll
                for (int nt = 0; nt < 4; ++nt)
                    acc[mt][nt] = __builtin_amdgcn_mfma_f32_16x16x32_bf16(
                        af[mt], bfv[nt], acc[mt][nt], 0, 0, 0);
        }
        __syncthreads();
    }
    float* gp = Gpart + (size_t)bz * 512 * 512;
    #pragma unroll
    for (int mt = 0; mt < 4; ++mt)
        #pragma unroll
        for (int r = 0; r < 4; ++r) {
            const int d1 = d1base + wy * 64 + mt * 16 + q * 4 + r;
            #pragma unroll
            for (int nt = 0; nt < 4; ++nt) {
                const int d2 = d2base + wx * 64 + nt * 16 + r15;
                gp[d1 * 512 + d2] = acc[mt][nt][r];
            }
        }
}

__global__ void gram_merge_kernel(const float* __restrict__ Gpart,
                                  float* __restrict__ G) {
    const int idx = blockIdx.x * 256 + threadIdx.x;   // 1024 blocks
    float s = 0.f;
    for (int b = 0; b < 32; ++b) s += Gpart[(size_t)b * 512 * 512 + idx];
    G[idx] = s;
}

// ---- per-row closed-form stats -> alpha, shift ---------------------------

__launch_bounds__(256)
__global__ void gu_kernel(const unsigned short* __restrict__ Abf,
                          const float* __restrict__ G,
                          const float* __restrict__ Svec,
                          const float* __restrict__ Tvec,
                          const double* __restrict__ E12,
                          const float* __restrict__ cvec,
                          const float* __restrict__ posv,
                          const int* __restrict__ pairs,
                          float* __restrict__ alpha_v,
                          float* __restrict__ shift_v) {
    __shared__ float u[8][512];
    __shared__ float red[8][3][4];
    const int t = threadIdx.x;
    const int lane = t & 63, wave = t >> 6;
    const int r0 = blockIdx.x * 8;
    #pragma unroll
    for (int p = 0; p < 8; ++p) {
        unsigned pk = *(const unsigned*)(Abf + (size_t)(r0 + p) * DIM + 2 * t);
        u[p][2 * t]     = bf2f((unsigned short)(pk & 0xffffu));
        u[p][2 * t + 1] = bf2f((unsigned short)(pk >> 16));
    }
    __syncthreads();
    float acc0[8], acc1[8];
    #pragma unroll
    for (int p = 0; p < 8; ++p) { acc0[p] = 0.f; acc1[p] = 0.f; }
    for (int d1 = 0; d1 < 512; ++d1) {
        const float2 g = *(const float2*)(G + d1 * 512 + 2 * t);
        #pragma unroll
        for (int p = 0; p < 8; ++p) {
            const float up = u[p][d1];
            acc0[p] += up * g.x;
            acc1[p] += up * g.y;
        }
    }
    const float sv0 = Svec[2 * t], sv1 = Svec[2 * t + 1];
    const float tv0 = Tvec[2 * t], tv1 = Tvec[2 * t + 1];
    #pragma unroll
    for (int p = 0; p < 8; ++p) {
        const float u0 = u[p][2 * t], u1 = u[p][2 * t + 1];
        float pdS = u0 * sv0 + u1 * sv1;
        float pdT = u0 * tv0 + u1 * tv1;
        float pq  = u0 * acc0[p] + u1 * acc1[p];
        #pragma unroll
        for (int off = 1; off < 64; off <<= 1) {
            pdS += __shfl_xor(pdS, off);
            pdT += __shfl_xor(pdT, off);
            pq  += __shfl_xor(pq,  off);
        }
        if (lane == 0) {
            red[p][0][wave] = pdS;
            red[p][1][wave] = pdT;
            red[p][2][wave] = pq;
        }
    }
    __syncthreads();
    if (t < 8) {
        const int p = t;
        const double dS = (double)red[p][0][0] + red[p][0][1] + red[p][0][2] + red[p][0][3];
        const double dT = (double)red[p][1][0] + red[p][1][1] + red[p][1][2] + red[p][1][3];
        const double qq = (double)red[p][2][0] + red[p][2][1] + red[p][2][2] + red[p][2][3];
        const int row = r0 + p;
        const int pp  = row & (NPAIR - 1);
        const double c  = (double)cvec[row];
        const double E1 = E12[0], E2 = E12[1];
        const double N  = (double)NODES;
        double Sx  = N * c + 2.0 * dS - E1;
        double Sxx = (N * c * c - 2.0 * c * E1 + E2) + 4.0 * (c * dS - dT) + 4.0 * qq;
        const int li = pairs[2 * pp], ri = pairs[2 * pp + 1];
        const double pos = (double)posv[pp];
        if (li != ri) {
            const double x1 = pos + (double)GAMMA_F, x2 = (double)GAMMA_F;
            Sx  -= x1 + x2;
            Sxx -= x1 * x1 + x2 * x2;
        } else {
            Sx -= 2.0 * (double)GAMMA_F;   // value flips sign; square unchanged
        }
        const double mu  = Sx / N;
        const double var = Sxx / N - mu * mu;
        const double sd  = sqrt(fmax(var, 1e-30));
        const double al  = (double)LAMB_F / sd;
        alpha_v[row] = (float)al;
        shift_v[row] = (float)(al * mu + (double)SHIFT_F);
    }
}

// ---- the big GEMM (single pass) + shifted-exp partial epilogue -----------

__launch_bounds__(256, 2)
__global__ void gemm_kernel(const unsigned short* __restrict__ Abf,
                            const unsigned short* __restrict__ Ebf,
                            const float* __restrict__ cvec,
                            const float* __restrict__ esq,
                            const int*   __restrict__ pairs,
                            const float* __restrict__ alpha_v,
                            const float* __restrict__ shift_v,
                            float* __restrict__ psum) {
    __shared__ unsigned short ldsA[TM * BK];  // 16 KB
    __shared__ unsigned short ldsB[TN * BK];  // 16 KB
    __shared__ float red_s[2][TM];
    __shared__ float alsh[TM], csh[TM], cmsh[TM];
    __shared__ int   lish[TM], rish[TM];

    const int tid  = threadIdx.x;
    const int lane = tid & 63;
    const int wave = tid >> 6;
    const int wx = wave & 1;
    const int wy = wave >> 1;
    const int nb = blockIdx.x;
    const int n0 = nb * TN;
    const int m0 = blockIdx.y * TM;

    if (tid < TM) {
        const int gm = m0 + tid;
        alsh[tid] = alpha_v[gm];
        csh[tid]  = shift_v[gm];
        cmsh[tid] = cvec[gm];
        const int p = gm & (NPAIR - 1);
        lish[tid] = pairs[2 * p];
        rish[tid] = pairs[2 * p + 1];
    }

    f32x4 zero4 = {0.f, 0.f, 0.f, 0.f};
    f32x4 acc[4][4];
    #pragma unroll
    for (int i = 0; i < 4; ++i)
        #pragma unroll
        for (int j = 0; j < 4; ++j) acc[i][j] = zero4;

    const int lrow   = lane >> 3;
    const int lchunk = lane & 7;
    const int r15 = lane & 15;
    const int q   = lane >> 4;

    for (int kt = 0; kt < DIM / BK; ++kt) {
        const int kb = kt * BK;
        #pragma unroll
        for (int j = 0; j < 4; ++j) {
            const int rbase = (wave * 4 + j) * 8;
            const int row   = rbase + lrow;
            const int gch   = lchunk ^ (row & 7);
            gload_lds16(Abf + ((size_t)(m0 + row) * DIM + kb + gch * 8), &ldsA[rbase * BK]);
            gload_lds16(Ebf + ((size_t)(n0 + row) * DIM + kb + gch * 8), &ldsB[rbase * BK]);
        }
        __builtin_amdgcn_s_waitcnt(0);
        __syncthreads();
        #pragma unroll
        for (int h = 0; h < 2; ++h) {
            short8 af[4], bfr[4];
            #pragma unroll
            for (int mt = 0; mt < 4; ++mt) {
                int row = wy * 64 + mt * 16 + r15;
                int c   = (h * 4 + q) ^ (row & 7);
                af[mt] = *(const short8*)&ldsA[row * BK + c * 8];
            }
            #pragma unroll
            for (int nt = 0; nt < 4; ++nt) {
                int row = wx * 64 + nt * 16 + r15;
                int c   = (h * 4 + q) ^ (row & 7);
                bfr[nt] = *(const short8*)&ldsB[row * BK + c * 8];
            }
            #pragma unroll
            for (int mt = 0; mt < 4; ++mt)
                #pragma unroll
                for (int nt = 0; nt < 4; ++nt)
                    acc[mt][nt] = __builtin_amdgcn_mfma_f32_16x16x32_bf16(
                        af[mt], bfr[nt], acc[mt][nt], 0, 0, 0);
        }
        __syncthreads();
    }

    // epilogue: se = sum exp(al*x - C); C absorbs mu and 7-sigma headroom
    #pragma unroll
    for (int mt = 0; mt < 4; ++mt) {
        #pragma unroll
        for (int r = 0; r < 4; ++r) {
            const int rit = wy * 64 + mt * 16 + q * 4 + r;
            const float cm = cmsh[rit];
            const float al = alsh[rit];
            const float Cc = csh[rit];
            const int li = lish[rit], ri = rish[rit];
            float se = 0.f;
            #pragma unroll
            for (int nt = 0; nt < 4; ++nt) {
                const int gn = n0 + wx * 64 + nt * 16 + r15;
                float xv = cm + 2.0f * acc[mt][nt][r] - esq[gn];
                float msk = 1.0f - (float)(gn == li) - (float)(gn == ri);
                xv *= msk;
                float term = __expf(fmaf(al, xv, -Cc));
                se += (gn < NODES) ? term : 0.f;
            }
            #pragma unroll
            for (int o = 1; o < 16; o <<= 1) se += __shfl_xor(se, o);
            if (r15 == 0) red_s[wx][rit] = se;
        }
    }
    __syncthreads();
    if (tid < TM) {
        psum[(size_t)nb * MROWS + m0 + tid] = red_s[0][tid] + red_s[1][tid];
    }
}

// ---- partial-sum tree over nb, then loss, then mean ----------------------

__global__ void lse_part_kernel(const float* __restrict__ psum,
                                float* __restrict__ lsep) {
    const int row = blockIdx.x * 256 + threadIdx.x;   // 16 x 256 = 4096
    const int c   = blockIdx.y;                       // 4 chunks
    const int nb0 = c * 196;
    const int nb1 = (nb0 + 196 < NB) ? nb0 + 196 : NB;
    float s = 0.f;
    for (int nb = nb0; nb < nb1; ++nb)
        s += psum[(size_t)nb * MROWS + row];
    lsep[(size_t)c * MROWS + row] = s;
}

__global__ void loss_kernel(const float* __restrict__ lsep,
                            float* __restrict__ loss_v) {
    const int row = blockIdx.x * 256 + threadIdx.x;   // 16 blocks
    const float s = lsep[row] + lsep[MROWS + row]
                  + lsep[2 * MROWS + row] + lsep[3 * MROWS + row];
    loss_v[row] = (TAU_F + SHIFT_F) + logf(s);
}

__global__ void final_kernel(const float* __restrict__ loss_v,
                             float* __restrict__ out) {
    __shared__ double wpart[4];
    int t = threadIdx.x;
    double s = 0.0;
    for (int i = t; i < MROWS; i += 256)
        s += (double)loss_v[i];
    #pragma unroll
    for (int off = 1; off < 64; off <<= 1) s += __shfl_xor(s, off);
    if ((t & 63) == 0) wpart[t >> 6] = s;
    __syncthreads();
    if (t == 0) out[0] = (float)((wpart[0] + wpart[1] + wpart[2] + wpart[3]) / (double)NPAIR);
}

// ---- host ----------------------------------------------------------------

extern "C" void kernel_launch(void* const* d_in, const int* in_sizes, int n_in,
                              void* d_out, int out_size, void* d_ws, size_t ws_size,
                              hipStream_t stream) {
    const int*   pairs = (const int*)d_in[0];
    const float* emb   = (const float*)d_in[1];
    float* out = (float*)d_out;

    char* ws = (char*)d_ws;
    size_t off = 0;
    auto alloc = [&](size_t bytes) -> void* {
        void* p = ws + off;
        off += (bytes + 255) & ~(size_t)255;
        return p;
    };
    unsigned short* Ebf  = (unsigned short*)alloc((size_t)NPAD * DIM * 2);
    unsigned short* EbfT = (unsigned short*)alloc((size_t)DIM * NPAD * 2);
    unsigned short* Abf  = (unsigned short*)alloc((size_t)MROWS * DIM * 2);
    float*  esq     = (float*)alloc((size_t)NPAD * 4);
    float*  cvec    = (float*)alloc((size_t)MROWS * 4);
    float*  posv    = (float*)alloc((size_t)NPAIR * 4);
    float*  Spart   = (float*)alloc((size_t)512 * DIM * 4);
    float*  Tpart   = (float*)alloc((size_t)512 * DIM * 4);
    float*  E1part  = (float*)alloc((size_t)512 * 4);
    float*  E2part  = (float*)alloc((size_t)512 * 4);
    float*  Svec    = (float*)alloc((size_t)DIM * 4);
    float*  Tvec    = (float*)alloc((size_t)DIM * 4);
    double* E12     = (double*)alloc(2 * sizeof(double));
    float*  G       = (float*)alloc((size_t)512 * 512 * 4);
    float*  alpha_v = (float*)alloc((size_t)MROWS * 4);
    float*  shift_v = (float*)alloc((size_t)MROWS * 4);
    float*  lsep    = (float*)alloc((size_t)4 * MROWS * 4);
    float*  loss_v  = (float*)alloc((size_t)MROWS * 4);
    // union region: Gram partials (32 MB), then psum (12.8 MB) after gram_merge
    char* uni = (char*)alloc((size_t)32 * 512 * 512 * 4);
    float* Gpart = (float*)uni;
    float* psum  = (float*)uni;
    if (off > ws_size) return;  // workspace too small — fail visibly

    convert_stats_kernel<<<512, 256, 0, stream>>>(emb, Ebf, esq,
                                                  Spart, Tpart, E1part, E2part);
    stats_merge_kernel<<<1, 1024, 0, stream>>>(Spart, Tpart, E1part, E2part,
                                               Svec, Tvec, E12);
    gather_kernel<<<NPAIR, 64, 0, stream>>>(pairs, emb, Abf, cvec, posv);

    transpose_kernel<<<dim3(NPAD / 256, DIM / 64), 256, 0, stream>>>(Ebf, EbfT);
    gram_kernel<<<dim3(4, 4, 32), 256, 0, stream>>>(EbfT, Gpart);
    gram_merge_kernel<<<1024, 256, 0, stream>>>(Gpart, G);
    gu_kernel<<<MROWS / 8, 256, 0, stream>>>(Abf, G, Svec, Tvec, E12,
                                             cvec, posv, pairs, alpha_v, shift_v);

    gemm_kernel<<<dim3(NB, MPAGES), 256, 0, stream>>>(Abf, Ebf, cvec, esq, pairs,
                                                      alpha_v, shift_v, psum);
    lse_part_kernel<<<dim3(16, 4), 256, 0, stream>>>(psum, lsep);
    loss_kernel<<<16, 256, 0, stream>>>(lsep, loss_v);
    final_kernel<<<1, 256, 0, stream>>>(loss_v, out);
}

// Round 4
// 1093.393 us; speedup vs baseline: 1.0865x; 1.0865x over previous
//
#include <hip/hip_runtime.h>
#include <stdint.h>

#define NODES   100000
#define NPAD    100096   // 782 * 128 = 1564 * 64
#define DIM     512
#define NPAIR   2048
#define MROWS   4096     // 2048 l-rows + 2048 r-rows
#define NB      782      // NPAD / TN
#define GAMMA_F 3.0f
#define LAMB_F  20.0f
#define TAU_F   8.0f
#define SHIFT_F 140.0f   // LAMB * 7 (7-sigma LSE shift)

#define TM 128
#define TN 128
#define BK 64

typedef __attribute__((ext_vector_type(8))) short          short8;
typedef __attribute__((ext_vector_type(8))) unsigned short ushort8;
typedef __attribute__((ext_vector_type(4))) float          f32x4;

// ---- helpers -------------------------------------------------------------

__device__ __forceinline__ unsigned short f2bf(float f) {
    unsigned u = __float_as_uint(f);
    u += 0x7FFFu + ((u >> 16) & 1u);   // RNE
    return (unsigned short)(u >> 16);
}
__device__ __forceinline__ float bf2f(unsigned short h) {
    return __uint_as_float(((unsigned)h) << 16);
}

// async global->LDS, 16B per lane; lds dest = wave-uniform base + lane*16
__device__ __forceinline__ void gload_lds16(const void* g, void* l) {
    unsigned lofs = (unsigned)__builtin_amdgcn_readfirstlane((unsigned)(uintptr_t)l);
    auto lp = reinterpret_cast<__attribute__((address_space(3))) unsigned*>(lofs);
    auto gp = (const __attribute__((address_space(1))) unsigned*)g;
    __builtin_amdgcn_global_load_lds(gp, lp, 16, 0, 0);
}

// ---- fused convert + stats partials --------------------------------------

__global__ void convert_stats_kernel(const float* __restrict__ emb,
                                     unsigned short* __restrict__ Ebf,
                                     float* __restrict__ esq,
                                     float* __restrict__ Spart,
                                     float* __restrict__ Tpart,
                                     float* __restrict__ E1part,
                                     float* __restrict__ E2part) {
    __shared__ float Sl[4][512];
    __shared__ float Tl[4][512];
    __shared__ float ew[8];
    const int b = blockIdx.x, t = threadIdx.x;
    const int lane = t & 63, wave = t >> 6;
    const int r0 = b * 196;
    float sacc[8], tacc[8];
    #pragma unroll
    for (int k = 0; k < 8; ++k) { sacc[k] = 0.f; tacc[k] = 0.f; }
    float e1 = 0.f, e2 = 0.f;
    for (int i = 0; i < 49; ++i) {
        const int row = r0 + i * 4 + wave;
        if (row >= NPAD) continue;
        const bool real = row < NODES;
        float v[8];
        float ss = 0.f;
        if (real) {
            const float4* p = (const float4*)(emb + (size_t)row * DIM + lane * 8);
            float4 a = p[0], bb = p[1];
            v[0]=a.x; v[1]=a.y; v[2]=a.z; v[3]=a.w;
            v[4]=bb.x; v[5]=bb.y; v[6]=bb.z; v[7]=bb.w;
            #pragma unroll
            for (int k = 0; k < 8; ++k) ss += v[k] * v[k];
        } else {
            #pragma unroll
            for (int k = 0; k < 8; ++k) v[k] = 0.f;
        }
        #pragma unroll
        for (int o = 1; o < 64; o <<= 1) ss += __shfl_xor(ss, o);
        ushort8 o8;
        float vr[8];
        #pragma unroll
        for (int k = 0; k < 8; ++k) { o8[k] = f2bf(v[k]); vr[k] = bf2f(o8[k]); }
        *(ushort8*)(Ebf + (size_t)row * DIM + lane * 8) = o8;
        if (lane == 0) esq[row] = ss;
        if (real) {
            #pragma unroll
            for (int k = 0; k < 8; ++k) { sacc[k] += vr[k]; tacc[k] += ss * vr[k]; }
            if (lane == 0) { e1 += ss; e2 += ss * ss; }
        }
    }
    #pragma unroll
    for (int k = 0; k < 8; ++k) {
        Sl[wave][lane * 8 + k] = sacc[k];
        Tl[wave][lane * 8 + k] = tacc[k];
    }
    if (lane == 0) { ew[wave] = e1; ew[4 + wave] = e2; }
    __syncthreads();
    #pragma unroll
    for (int kk = 0; kk < 2; ++kk) {
        const int d = 2 * t + kk;
        Spart[(size_t)b * 512 + d] = Sl[0][d] + Sl[1][d] + Sl[2][d] + Sl[3][d];
        Tpart[(size_t)b * 512 + d] = Tl[0][d] + Tl[1][d] + Tl[2][d] + Tl[3][d];
    }
    if (t == 0) E1part[b] = ew[0] + ew[1] + ew[2] + ew[3];
    if (t == 1) E2part[b] = ew[4] + ew[5] + ew[6] + ew[7];
}

// parallel merge: blocks 0-15 -> Svec, 16-31 -> Tvec, 32/33 -> E12
__global__ void stats_merge_kernel(const float* __restrict__ Spart,
                                   const float* __restrict__ Tpart,
                                   const float* __restrict__ E1part,
                                   const float* __restrict__ E2part,
                                   float* __restrict__ Svec,
                                   float* __restrict__ Tvec,
                                   double* __restrict__ E12) {
    const int bid = blockIdx.x, t = threadIdx.x;   // 34 x 256
    if (bid < 32) {
        __shared__ float part[8][32];
        const int col = (bid & 15) * 32 + (t & 31);
        const int seg = t >> 5;                    // 8 segments x 64 rows
        const float* src = (bid < 16) ? Spart : Tpart;
        float s = 0.f;
        const int b0 = seg * 64;
        for (int b = b0; b < b0 + 64; ++b) s += src[(size_t)b * 512 + col];
        part[seg][t & 31] = s;
        __syncthreads();
        if (t < 32) {
            float r = 0.f;
            #pragma unroll
            for (int g = 0; g < 8; ++g) r += part[g][t];
            const int c2 = (bid & 15) * 32 + t;
            if (bid < 16) Svec[c2] = r; else Tvec[c2] = r;
        }
    } else {
        __shared__ double w[4];
        const float* src = (bid == 32) ? E1part : E2part;
        double s = (double)src[t] + (double)src[t + 256];
        #pragma unroll
        for (int o = 1; o < 64; o <<= 1) s += __shfl_xor(s, o);
        if ((t & 63) == 0) w[t >> 6] = s;
        __syncthreads();
        if (t == 0) E12[bid - 32] = w[0] + w[1] + w[2] + w[3];
    }
}

// gather A rows (bf16) + c[m] = pos - |a|^2 + gamma ; posv[p] = pos
__global__ void gather_kernel(const int* __restrict__ pairs,
                              const float* __restrict__ emb,
                              unsigned short* __restrict__ Abf,
                              float* __restrict__ cvec,
                              float* __restrict__ posv) {
    const int p    = blockIdx.x;
    const int lane = threadIdx.x;
    const int li = pairs[2 * p], ri = pairs[2 * p + 1];
    const float4* pl = (const float4*)(emb + (size_t)li * DIM + lane * 8);
    const float4* pr = (const float4*)(emb + (size_t)ri * DIM + lane * 8);
    float4 a0 = pl[0], a1 = pl[1];
    float4 b0 = pr[0], b1 = pr[1];
    float la[8] = {a0.x,a0.y,a0.z,a0.w,a1.x,a1.y,a1.z,a1.w};
    float lb[8] = {b0.x,b0.y,b0.z,b0.w,b1.x,b1.y,b1.z,b1.w};
    float sa = 0.f, sb = 0.f, sd = 0.f;
    ushort8 oa, ob;
    #pragma unroll
    for (int i = 0; i < 8; ++i) {
        sa += la[i] * la[i];
        sb += lb[i] * lb[i];
        float d = la[i] - lb[i];
        sd += d * d;
        oa[i] = f2bf(la[i]);
        ob[i] = f2bf(lb[i]);
    }
    *(ushort8*)(Abf + (size_t)p * DIM + lane * 8)            = oa;
    *(ushort8*)(Abf + (size_t)(NPAIR + p) * DIM + lane * 8)  = ob;
    #pragma unroll
    for (int off = 1; off < 64; off <<= 1) {
        sa += __shfl_xor(sa, off);
        sb += __shfl_xor(sb, off);
        sd += __shfl_xor(sd, off);
    }
    if (lane == 0) {
        cvec[p]         = sd - sa + GAMMA_F;
        cvec[NPAIR + p] = sd - sb + GAMMA_F;
        posv[p]         = sd;
    }
}

// ---- Gram GEMM: Gpart[bz] = partial E^T E --------------------------------
// R0 structure, with group-padded LDS: group = 4 rows x 128 u16 (one
// gload_lds16 per wave, contiguous), stride GPAD=520 u16 -> the four
// q-groups of a fragment read land on disjoint bank octets (was 4-way
// dword conflict at stride 128).

#define GPAD 520   // 4*128 + 8

__launch_bounds__(256, 2)
__global__ void gram_kernel(const unsigned short* __restrict__ Ebf,
                            float* __restrict__ Gpart) {
    __shared__ unsigned short ldsA[16 * GPAD];
    __shared__ unsigned short ldsB[16 * GPAD];
    const int tid  = threadIdx.x;
    const int lane = tid & 63;
    const int wave = tid >> 6;
    const int wx = wave & 1, wy = wave >> 1;
    const int d1base = blockIdx.y * 128;
    const int d2base = blockIdx.x * 128;
    const int bz = blockIdx.z;
    const int r15 = lane & 15, q = lane >> 4;

    f32x4 zero4 = {0.f, 0.f, 0.f, 0.f};
    f32x4 acc[4][4];
    #pragma unroll
    for (int i = 0; i < 4; ++i)
        #pragma unroll
        for (int j = 0; j < 4; ++j) acc[i][j] = zero4;

    for (int jc = bz; jc < NPAD / 64; jc += 32) {
        const int j0 = jc * 64;
        #pragma unroll
        for (int ii = 0; ii < 4; ++ii) {
            const int iss = wave * 4 + ii;
            const int row = iss * 4 + (lane >> 4);
            gload_lds16(Ebf + (size_t)(j0 + row) * DIM + d1base + (lane & 15) * 8,
                        &ldsA[iss * GPAD]);
            gload_lds16(Ebf + (size_t)(j0 + row) * DIM + d2base + (lane & 15) * 8,
                        &ldsB[iss * GPAD]);
        }
        __builtin_amdgcn_s_waitcnt(0);
        __syncthreads();
        #pragma unroll
        for (int h = 0; h < 2; ++h) {
            short8 af[4], bfv[4];
            #pragma unroll
            for (int mt = 0; mt < 4; ++mt) {
                const int m = wy * 64 + mt * 16 + r15;
                #pragma unroll
                for (int i = 0; i < 8; ++i) {
                    const int r = h * 32 + q * 8 + i;
                    af[mt][i] = (short)ldsA[(r >> 2) * GPAD + (r & 3) * 128 + m];
                }
            }
            #pragma unroll
            for (int nt = 0; nt < 4; ++nt) {
                const int n = wx * 64 + nt * 16 + r15;
                #pragma unroll
                for (int i = 0; i < 8; ++i) {
                    const int r = h * 32 + q * 8 + i;
                    bfv[nt][i] = (short)ldsB[(r >> 2) * GPAD + (r & 3) * 128 + n];
                }
            }
            #pragma unroll
            for (int mt = 0; mt < 4; ++mt)
                #pragma unroll
                for (int nt = 0; nt < 4; ++nt)
                    acc[mt][nt] = __builtin_amdgcn_mfma_f32_16x16x32_bf16(
                        af[mt], bfv[nt], acc[mt][nt], 0, 0, 0);
        }
        __syncthreads();
    }
    float* gp = Gpart + (size_t)bz * 512 * 512;
    #pragma unroll
    for (int mt = 0; mt < 4; ++mt)
        #pragma unroll
        for (int r = 0; r < 4; ++r) {
            const int d1 = d1base + wy * 64 + mt * 16 + q * 4 + r;
            #pragma unroll
            for (int nt = 0; nt < 4; ++nt) {
                const int d2 = d2base + wx * 64 + nt * 16 + r15;
                gp[d1 * 512 + d2] = acc[mt][nt][r];
            }
        }
}

__global__ void gram_merge_kernel(const float* __restrict__ Gpart,
                                  float* __restrict__ G) {
    const int idx = blockIdx.x * 256 + threadIdx.x;   // 1024 blocks
    float s = 0.f;
    for (int b = 0; b < 32; ++b) s += Gpart[(size_t)b * 512 * 512 + idx];
    G[idx] = s;
}

// ---- per-row closed-form stats -> alpha, shift ---------------------------

__launch_bounds__(256)
__global__ void gu_kernel(const unsigned short* __restrict__ Abf,
                          const float* __restrict__ G,
                          const float* __restrict__ Svec,
                          const float* __restrict__ Tvec,
                          const double* __restrict__ E12,
                          const float* __restrict__ cvec,
                          const float* __restrict__ posv,
                          const int* __restrict__ pairs,
                          float* __restrict__ alpha_v,
                          float* __restrict__ shift_v) {
    __shared__ float u[8][512];
    __shared__ float red[8][3][4];
    const int t = threadIdx.x;
    const int lane = t & 63, wave = t >> 6;
    const int r0 = blockIdx.x * 8;
    #pragma unroll
    for (int p = 0; p < 8; ++p) {
        unsigned pk = *(const unsigned*)(Abf + (size_t)(r0 + p) * DIM + 2 * t);
        u[p][2 * t]     = bf2f((unsigned short)(pk & 0xffffu));
        u[p][2 * t + 1] = bf2f((unsigned short)(pk >> 16));
    }
    __syncthreads();
    float acc0[8], acc1[8];
    #pragma unroll
    for (int p = 0; p < 8; ++p) { acc0[p] = 0.f; acc1[p] = 0.f; }
    for (int d1 = 0; d1 < 512; ++d1) {
        const float2 g = *(const float2*)(G + d1 * 512 + 2 * t);
        #pragma unroll
        for (int p = 0; p < 8; ++p) {
            const float up = u[p][d1];
            acc0[p] += up * g.x;
            acc1[p] += up * g.y;
        }
    }
    const float sv0 = Svec[2 * t], sv1 = Svec[2 * t + 1];
    const float tv0 = Tvec[2 * t], tv1 = Tvec[2 * t + 1];
    #pragma unroll
    for (int p = 0; p < 8; ++p) {
        const float u0 = u[p][2 * t], u1 = u[p][2 * t + 1];
        float pdS = u0 * sv0 + u1 * sv1;
        float pdT = u0 * tv0 + u1 * tv1;
        float pq  = u0 * acc0[p] + u1 * acc1[p];
        #pragma unroll
        for (int off = 1; off < 64; off <<= 1) {
            pdS += __shfl_xor(pdS, off);
            pdT += __shfl_xor(pdT, off);
            pq  += __shfl_xor(pq,  off);
        }
        if (lane == 0) {
            red[p][0][wave] = pdS;
            red[p][1][wave] = pdT;
            red[p][2][wave] = pq;
        }
    }
    __syncthreads();
    if (t < 8) {
        const int p = t;
        const double dS = (double)red[p][0][0] + red[p][0][1] + red[p][0][2] + red[p][0][3];
        const double dT = (double)red[p][1][0] + red[p][1][1] + red[p][1][2] + red[p][1][3];
        const double qq = (double)red[p][2][0] + red[p][2][1] + red[p][2][2] + red[p][2][3];
        const int row = r0 + p;
        const int pp  = row & (NPAIR - 1);
        const double c  = (double)cvec[row];
        const double E1 = E12[0], E2 = E12[1];
        const double N  = (double)NODES;
        double Sx  = N * c + 2.0 * dS - E1;
        double Sxx = (N * c * c - 2.0 * c * E1 + E2) + 4.0 * (c * dS - dT) + 4.0 * qq;
        const int li = pairs[2 * pp], ri = pairs[2 * pp + 1];
        const double pos = (double)posv[pp];
        if (li != ri) {
            const double x1 = pos + (double)GAMMA_F, x2 = (double)GAMMA_F;
            Sx  -= x1 + x2;
            Sxx -= x1 * x1 + x2 * x2;
        } else {
            Sx -= 2.0 * (double)GAMMA_F;   // value flips sign; square unchanged
        }
        const double mu  = Sx / N;
        const double var = Sxx / N - mu * mu;
        const double sd  = sqrt(fmax(var, 1e-30));
        const double al  = (double)LAMB_F / sd;
        alpha_v[row] = (float)al;
        shift_v[row] = (float)(al * mu + (double)SHIFT_F);
    }
}

// ---- the big GEMM, XCD-local paged: each block owns (nb, page-group) -----
// Mapping assumes dispatch d -> XCD d%8 (perf heuristic only): XCD x runs
// jobs j = x*782..x*782+781 in order; nb = j>>3 gives each XCD a contiguous
// ~98-nb band of B-panels, and the 8 page-groups of one nb run back-to-back
// on that XCD -> B staged from HBM ~once, re-stages are L2 hits, so the
// per-K-tile vmcnt(0) drain waits on ~250-cycle L2 latency instead of
// ~900-cycle HBM latency.

__launch_bounds__(256, 2)
__global__ void gemm_kernel(const unsigned short* __restrict__ Abf,
                            const unsigned short* __restrict__ Ebf,
                            const float* __restrict__ cvec,
                            const float* __restrict__ esq,
                            const int*   __restrict__ pairs,
                            const float* __restrict__ alpha_v,
                            const float* __restrict__ shift_v,
                            float* __restrict__ psum) {
    __shared__ unsigned short ldsA[TM * BK];  // 16 KB
    __shared__ unsigned short ldsB[TN * BK];  // 16 KB
    __shared__ float red_s[2][TM];
    __shared__ float alsh[TM], csh[TM], cmsh[TM];
    __shared__ int   lish[TM], rish[TM];

    const int tid  = threadIdx.x;
    const int lane = tid & 63;
    const int wave = tid >> 6;
    const int wx = wave & 1;
    const int wy = wave >> 1;

    const int d = blockIdx.x;                 // 0..6255
    const int j = (d & 7) * 782 + (d >> 3);
    const int nb  = j >> 3;                   // 0..781
    const int mpg = j & 7;                    // page-group: 4 M-pages each
    const int n0  = nb * TN;

    const int lrow   = lane >> 3;
    const int lchunk = lane & 7;
    const int r15 = lane & 15;
    const int q   = lane >> 4;

    // per-nb epilogue operands (hoisted out of the page loop)
    float eqv[4];
    int   gnv[4];
    #pragma unroll
    for (int nt = 0; nt < 4; ++nt) {
        const int gn = n0 + wx * 64 + nt * 16 + r15;
        gnv[nt] = gn;
        eqv[nt] = esq[gn];
    }

    for (int pg = 0; pg < 4; ++pg) {
        const int m0 = (mpg * 4 + pg) * TM;

        if (tid < TM) {
            const int gm = m0 + tid;
            alsh[tid] = alpha_v[gm];
            csh[tid]  = shift_v[gm];
            cmsh[tid] = cvec[gm];
            const int p = gm & (NPAIR - 1);
            lish[tid] = pairs[2 * p];
            rish[tid] = pairs[2 * p + 1];
        }

        f32x4 zero4 = {0.f, 0.f, 0.f, 0.f};
        f32x4 acc[4][4];
        #pragma unroll
        for (int i = 0; i < 4; ++i)
            #pragma unroll
            for (int jj = 0; jj < 4; ++jj) acc[i][jj] = zero4;

        for (int kt = 0; kt < DIM / BK; ++kt) {
            const int kb = kt * BK;
            #pragma unroll
            for (int jj = 0; jj < 4; ++jj) {
                const int rbase = (wave * 4 + jj) * 8;
                const int row   = rbase + lrow;
                const int gch   = lchunk ^ (row & 7);
                gload_lds16(Abf + ((size_t)(m0 + row) * DIM + kb + gch * 8), &ldsA[rbase * BK]);
                gload_lds16(Ebf + ((size_t)(n0 + row) * DIM + kb + gch * 8), &ldsB[rbase * BK]);
            }
            __builtin_amdgcn_s_waitcnt(0);
            __syncthreads();
            #pragma unroll
            for (int h = 0; h < 2; ++h) {
                short8 af[4], bfr[4];
                #pragma unroll
                for (int mt = 0; mt < 4; ++mt) {
                    int row = wy * 64 + mt * 16 + r15;
                    int c   = (h * 4 + q) ^ (row & 7);
                    af[mt] = *(const short8*)&ldsA[row * BK + c * 8];
                }
                #pragma unroll
                for (int nt = 0; nt < 4; ++nt) {
                    int row = wx * 64 + nt * 16 + r15;
                    int c   = (h * 4 + q) ^ (row & 7);
                    bfr[nt] = *(const short8*)&ldsB[row * BK + c * 8];
                }
                #pragma unroll
                for (int mt = 0; mt < 4; ++mt)
                    #pragma unroll
                    for (int nt = 0; nt < 4; ++nt)
                        acc[mt][nt] = __builtin_amdgcn_mfma_f32_16x16x32_bf16(
                            af[mt], bfr[nt], acc[mt][nt], 0, 0, 0);
            }
            __syncthreads();
        }

        // epilogue: se = sum exp(al*x - C); C absorbs mu and 7-sigma headroom
        #pragma unroll
        for (int mt = 0; mt < 4; ++mt) {
            #pragma unroll
            for (int r = 0; r < 4; ++r) {
                const int rit = wy * 64 + mt * 16 + q * 4 + r;
                const float cm = cmsh[rit];
                const float al = alsh[rit];
                const float Cc = csh[rit];
                const int li = lish[rit], ri = rish[rit];
                float se = 0.f;
                #pragma unroll
                for (int nt = 0; nt < 4; ++nt) {
                    float xv = cm + 2.0f * acc[mt][nt][r] - eqv[nt];
                    float msk = 1.0f - (float)(gnv[nt] == li) - (float)(gnv[nt] == ri);
                    xv *= msk;
                    float term = __expf(fmaf(al, xv, -Cc));
                    se += (gnv[nt] < NODES) ? term : 0.f;
                }
                #pragma unroll
                for (int o = 1; o < 16; o <<= 1) se += __shfl_xor(se, o);
                if (r15 == 0) red_s[wx][rit] = se;
            }
        }
        __syncthreads();
        if (tid < TM) {
            psum[(size_t)nb * MROWS + m0 + tid] = red_s[0][tid] + red_s[1][tid];
        }
    }
}

// ---- fused partial-sum + loss, then mean ---------------------------------

__global__ void lse_loss_kernel(const float* __restrict__ psum,
                                float* __restrict__ loss_v) {
    const int row = blockIdx.x * 256 + threadIdx.x;   // 16 blocks
    float s = 0.f;
    for (int nb = 0; nb < NB; ++nb)
        s += psum[(size_t)nb * MROWS + row];
    loss_v[row] = (TAU_F + SHIFT_F) + logf(s);
}

__global__ void final_kernel(const float* __restrict__ loss_v,
                             float* __restrict__ out) {
    __shared__ double wpart[4];
    int t = threadIdx.x;
    double s = 0.0;
    for (int i = t; i < MROWS; i += 256)
        s += (double)loss_v[i];
    #pragma unroll
    for (int off = 1; off < 64; off <<= 1) s += __shfl_xor(s, off);
    if ((t & 63) == 0) wpart[t >> 6] = s;
    __syncthreads();
    if (t == 0) out[0] = (float)((wpart[0] + wpart[1] + wpart[2] + wpart[3]) / (double)NPAIR);
}

// ---- host ----------------------------------------------------------------

extern "C" void kernel_launch(void* const* d_in, const int* in_sizes, int n_in,
                              void* d_out, int out_size, void* d_ws, size_t ws_size,
                              hipStream_t stream) {
    const int*   pairs = (const int*)d_in[0];
    const float* emb   = (const float*)d_in[1];
    float* out = (float*)d_out;

    char* ws = (char*)d_ws;
    size_t off = 0;
    auto alloc = [&](size_t bytes) -> void* {
        void* p = ws + off;
        off += (bytes + 255) & ~(size_t)255;
        return p;
    };
    unsigned short* Ebf = (unsigned short*)alloc((size_t)NPAD * DIM * 2);
    unsigned short* Abf = (unsigned short*)alloc((size_t)MROWS * DIM * 2);
    float*  esq     = (float*)alloc((size_t)NPAD * 4);
    float*  cvec    = (float*)alloc((size_t)MROWS * 4);
    float*  posv    = (float*)alloc((size_t)NPAIR * 4);
    float*  Spart   = (float*)alloc((size_t)512 * DIM * 4);
    float*  Tpart   = (float*)alloc((size_t)512 * DIM * 4);
    float*  E1part  = (float*)alloc((size_t)512 * 4);
    float*  E2part  = (float*)alloc((size_t)512 * 4);
    float*  Svec    = (float*)alloc((size_t)DIM * 4);
    float*  Tvec    = (float*)alloc((size_t)DIM * 4);
    double* E12     = (double*)alloc(2 * sizeof(double));
    float*  G       = (float*)alloc((size_t)512 * 512 * 4);
    float*  alpha_v = (float*)alloc((size_t)MROWS * 4);
    float*  shift_v = (float*)alloc((size_t)MROWS * 4);
    float*  loss_v  = (float*)alloc((size_t)MROWS * 4);
    // union region: Gram partials (32 MB), then psum (12.8 MB) after gram_merge
    char* uni = (char*)alloc((size_t)32 * 512 * 512 * 4);
    float* Gpart = (float*)uni;
    float* psum  = (float*)uni;
    if (off > ws_size) return;  // workspace too small — fail visibly

    convert_stats_kernel<<<512, 256, 0, stream>>>(emb, Ebf, esq,
                                                  Spart, Tpart, E1part, E2part);
    stats_merge_kernel<<<34, 256, 0, stream>>>(Spart, Tpart, E1part, E2part,
                                               Svec, Tvec, E12);
    gather_kernel<<<NPAIR, 64, 0, stream>>>(pairs, emb, Abf, cvec, posv);

    gram_kernel<<<dim3(4, 4, 32), 256, 0, stream>>>(Ebf, Gpart);
    gram_merge_kernel<<<1024, 256, 0, stream>>>(Gpart, G);
    gu_kernel<<<MROWS / 8, 256, 0, stream>>>(Abf, G, Svec, Tvec, E12,
                                             cvec, posv, pairs, alpha_v, shift_v);

    gemm_kernel<<<6256, 256, 0, stream>>>(Abf, Ebf, cvec, esq, pairs,
                                          alpha_v, shift_v, psum);
    lse_loss_kernel<<<16, 256, 0, stream>>>(psum, loss_v);
    final_kernel<<<1, 256, 0, stream>>>(loss_v, out);
}

// Round 6
// 978.959 us; speedup vs baseline: 1.2135x; 1.1169x over previous
//
#include <hip/hip_runtime.h>
#include <stdint.h>

#define NODES   100000
#define NPAD    100096   // 782 * 128 = 1564 * 64
#define DIM     512
#define NPAIR   2048
#define MROWS   4096     // 2048 l-rows + 2048 r-rows
#define NB      782      // NPAD / TN
#define MPAGES  32       // MROWS / TM
#define GAMMA_F 3.0f
#define LAMB_F  20.0f
#define TAU_F   8.0f
#define SHIFT_F 140.0f   // LAMB * 7 (7-sigma LSE shift)

#define TM 128
#define TN 128
#define BK 64

typedef __attribute__((ext_vector_type(8))) short          short8;
typedef __attribute__((ext_vector_type(8))) unsigned short ushort8;
typedef __attribute__((ext_vector_type(4))) float          f32x4;

// ---- helpers -------------------------------------------------------------

__device__ __forceinline__ unsigned short f2bf(float f) {
    unsigned u = __float_as_uint(f);
    u += 0x7FFFu + ((u >> 16) & 1u);   // RNE
    return (unsigned short)(u >> 16);
}
__device__ __forceinline__ float bf2f(unsigned short h) {
    return __uint_as_float(((unsigned)h) << 16);
}

// async global->LDS, 16B per lane; lds dest = wave-uniform base + lane*16
__device__ __forceinline__ void gload_lds16(const void* g, void* l) {
    unsigned lofs = (unsigned)__builtin_amdgcn_readfirstlane((unsigned)(uintptr_t)l);
    auto lp = reinterpret_cast<__attribute__((address_space(3))) unsigned*>(lofs);
    auto gp = (const __attribute__((address_space(1))) unsigned*)g;
    __builtin_amdgcn_global_load_lds(gp, lp, 16, 0, 0);
}

// ---- fused convert + stats partials --------------------------------------

__global__ void convert_stats_kernel(const float* __restrict__ emb,
                                     unsigned short* __restrict__ Ebf,
                                     float* __restrict__ esq,
                                     float* __restrict__ Spart,
                                     float* __restrict__ Tpart,
                                     float* __restrict__ E1part,
                                     float* __restrict__ E2part) {
    __shared__ float Sl[4][512];
    __shared__ float Tl[4][512];
    __shared__ float ew[8];
    const int b = blockIdx.x, t = threadIdx.x;
    const int lane = t & 63, wave = t >> 6;
    const int r0 = b * 196;
    float sacc[8], tacc[8];
    #pragma unroll
    for (int k = 0; k < 8; ++k) { sacc[k] = 0.f; tacc[k] = 0.f; }
    float e1 = 0.f, e2 = 0.f;
    for (int i = 0; i < 49; ++i) {
        const int row = r0 + i * 4 + wave;
        if (row >= NPAD) continue;
        const bool real = row < NODES;
        float v[8];
        float ss = 0.f;
        if (real) {
            const float4* p = (const float4*)(emb + (size_t)row * DIM + lane * 8);
            float4 a = p[0], bb = p[1];
            v[0]=a.x; v[1]=a.y; v[2]=a.z; v[3]=a.w;
            v[4]=bb.x; v[5]=bb.y; v[6]=bb.z; v[7]=bb.w;
            #pragma unroll
            for (int k = 0; k < 8; ++k) ss += v[k] * v[k];
        } else {
            #pragma unroll
            for (int k = 0; k < 8; ++k) v[k] = 0.f;
        }
        #pragma unroll
        for (int o = 1; o < 64; o <<= 1) ss += __shfl_xor(ss, o);
        ushort8 o8;
        float vr[8];
        #pragma unroll
        for (int k = 0; k < 8; ++k) { o8[k] = f2bf(v[k]); vr[k] = bf2f(o8[k]); }
        *(ushort8*)(Ebf + (size_t)row * DIM + lane * 8) = o8;
        if (lane == 0) esq[row] = ss;
        if (real) {
            #pragma unroll
            for (int k = 0; k < 8; ++k) { sacc[k] += vr[k]; tacc[k] += ss * vr[k]; }
            if (lane == 0) { e1 += ss; e2 += ss * ss; }
        }
    }
    #pragma unroll
    for (int k = 0; k < 8; ++k) {
        Sl[wave][lane * 8 + k] = sacc[k];
        Tl[wave][lane * 8 + k] = tacc[k];
    }
    if (lane == 0) { ew[wave] = e1; ew[4 + wave] = e2; }
    __syncthreads();
    #pragma unroll
    for (int kk = 0; kk < 2; ++kk) {
        const int d = 2 * t + kk;
        Spart[(size_t)b * 512 + d] = Sl[0][d] + Sl[1][d] + Sl[2][d] + Sl[3][d];
        Tpart[(size_t)b * 512 + d] = Tl[0][d] + Tl[1][d] + Tl[2][d] + Tl[3][d];
    }
    if (t == 0) E1part[b] = ew[0] + ew[1] + ew[2] + ew[3];
    if (t == 1) E2part[b] = ew[4] + ew[5] + ew[6] + ew[7];
}

// parallel merge: blocks 0-15 -> Svec, 16-31 -> Tvec, 32/33 -> E12
__global__ void stats_merge_kernel(const float* __restrict__ Spart,
                                   const float* __restrict__ Tpart,
                                   const float* __restrict__ E1part,
                                   const float* __restrict__ E2part,
                                   float* __restrict__ Svec,
                                   float* __restrict__ Tvec,
                                   double* __restrict__ E12) {
    const int bid = blockIdx.x, t = threadIdx.x;   // 34 x 256
    if (bid < 32) {
        __shared__ float part[8][32];
        const int col = (bid & 15) * 32 + (t & 31);
        const int seg = t >> 5;                    // 8 segments x 64 rows
        const float* src = (bid < 16) ? Spart : Tpart;
        float s = 0.f;
        const int b0 = seg * 64;
        for (int b = b0; b < b0 + 64; ++b) s += src[(size_t)b * 512 + col];
        part[seg][t & 31] = s;
        __syncthreads();
        if (t < 32) {
            float r = 0.f;
            #pragma unroll
            for (int g = 0; g < 8; ++g) r += part[g][t];
            const int c2 = (bid & 15) * 32 + t;
            if (bid < 16) Svec[c2] = r; else Tvec[c2] = r;
        }
    } else {
        __shared__ double w[4];
        const float* src = (bid == 32) ? E1part : E2part;
        double s = (double)src[t] + (double)src[t + 256];
        #pragma unroll
        for (int o = 1; o < 64; o <<= 1) s += __shfl_xor(s, o);
        if ((t & 63) == 0) w[t >> 6] = s;
        __syncthreads();
        if (t == 0) E12[bid - 32] = w[0] + w[1] + w[2] + w[3];
    }
}

// gather A rows (bf16) + c[m] = pos - |a|^2 + gamma ; posv[p] = pos
__global__ void gather_kernel(const int* __restrict__ pairs,
                              const float* __restrict__ emb,
                              unsigned short* __restrict__ Abf,
                              float* __restrict__ cvec,
                              float* __restrict__ posv) {
    const int p    = blockIdx.x;
    const int lane = threadIdx.x;
    const int li = pairs[2 * p], ri = pairs[2 * p + 1];
    const float4* pl = (const float4*)(emb + (size_t)li * DIM + lane * 8);
    const float4* pr = (const float4*)(emb + (size_t)ri * DIM + lane * 8);
    float4 a0 = pl[0], a1 = pl[1];
    float4 b0 = pr[0], b1 = pr[1];
    float la[8] = {a0.x,a0.y,a0.z,a0.w,a1.x,a1.y,a1.z,a1.w};
    float lb[8] = {b0.x,b0.y,b0.z,b0.w,b1.x,b1.y,b1.z,b1.w};
    float sa = 0.f, sb = 0.f, sd = 0.f;
    ushort8 oa, ob;
    #pragma unroll
    for (int i = 0; i < 8; ++i) {
        sa += la[i] * la[i];
        sb += lb[i] * lb[i];
        float d = la[i] - lb[i];
        sd += d * d;
        oa[i] = f2bf(la[i]);
        ob[i] = f2bf(lb[i]);
    }
    *(ushort8*)(Abf + (size_t)p * DIM + lane * 8)            = oa;
    *(ushort8*)(Abf + (size_t)(NPAIR + p) * DIM + lane * 8)  = ob;
    #pragma unroll
    for (int off = 1; off < 64; off <<= 1) {
        sa += __shfl_xor(sa, off);
        sb += __shfl_xor(sb, off);
        sd += __shfl_xor(sd, off);
    }
    if (lane == 0) {
        cvec[p]         = sd - sa + GAMMA_F;
        cvec[NPAIR + p] = sd - sb + GAMMA_F;
        posv[p]         = sd;
    }
}

// ---- Gram GEMM: Gpart[bz] = partial E^T E (R4-verbatim, green) -----------
// Group-padded LDS: group = 4 rows x 128 u16 (one gload_lds16 per wave,
// contiguous), stride GPAD=520 u16 -> the four q-groups of a fragment read
// land on disjoint bank octets (was 4-way dword conflict at stride 128).

#define GPAD 520   // 4*128 + 8

__launch_bounds__(256, 2)
__global__ void gram_kernel(const unsigned short* __restrict__ Ebf,
                            float* __restrict__ Gpart) {
    __shared__ unsigned short ldsA[16 * GPAD];
    __shared__ unsigned short ldsB[16 * GPAD];
    const int tid  = threadIdx.x;
    const int lane = tid & 63;
    const int wave = tid >> 6;
    const int wx = wave & 1, wy = wave >> 1;
    const int d1base = blockIdx.y * 128;
    const int d2base = blockIdx.x * 128;
    const int bz = blockIdx.z;
    const int r15 = lane & 15, q = lane >> 4;

    f32x4 zero4 = {0.f, 0.f, 0.f, 0.f};
    f32x4 acc[4][4];
    #pragma unroll
    for (int i = 0; i < 4; ++i)
        #pragma unroll
        for (int j = 0; j < 4; ++j) acc[i][j] = zero4;

    for (int jc = bz; jc < NPAD / 64; jc += 32) {
        const int j0 = jc * 64;
        #pragma unroll
        for (int ii = 0; ii < 4; ++ii) {
            const int iss = wave * 4 + ii;
            const int row = iss * 4 + (lane >> 4);
            gload_lds16(Ebf + (size_t)(j0 + row) * DIM + d1base + (lane & 15) * 8,
                        &ldsA[iss * GPAD]);
            gload_lds16(Ebf + (size_t)(j0 + row) * DIM + d2base + (lane & 15) * 8,
                        &ldsB[iss * GPAD]);
        }
        __builtin_amdgcn_s_waitcnt(0);
        __syncthreads();
        #pragma unroll
        for (int h = 0; h < 2; ++h) {
            short8 af[4], bfv[4];
            #pragma unroll
            for (int mt = 0; mt < 4; ++mt) {
                const int m = wy * 64 + mt * 16 + r15;
                #pragma unroll
                for (int i = 0; i < 8; ++i) {
                    const int r = h * 32 + q * 8 + i;
                    af[mt][i] = (short)ldsA[(r >> 2) * GPAD + (r & 3) * 128 + m];
                }
            }
            #pragma unroll
            for (int nt = 0; nt < 4; ++nt) {
                const int n = wx * 64 + nt * 16 + r15;
                #pragma unroll
                for (int i = 0; i < 8; ++i) {
                    const int r = h * 32 + q * 8 + i;
                    bfv[nt][i] = (short)ldsB[(r >> 2) * GPAD + (r & 3) * 128 + n];
                }
            }
            #pragma unroll
            for (int mt = 0; mt < 4; ++mt)
                #pragma unroll
                for (int nt = 0; nt < 4; ++nt)
                    acc[mt][nt] = __builtin_amdgcn_mfma_f32_16x16x32_bf16(
                        af[mt], bfv[nt], acc[mt][nt], 0, 0, 0);
        }
        __syncthreads();
    }
    float* gp = Gpart + (size_t)bz * 512 * 512;
    #pragma unroll
    for (int mt = 0; mt < 4; ++mt)
        #pragma unroll
        for (int r = 0; r < 4; ++r) {
            const int d1 = d1base + wy * 64 + mt * 16 + q * 4 + r;
            #pragma unroll
            for (int nt = 0; nt < 4; ++nt) {
                const int d2 = d2base + wx * 64 + nt * 16 + r15;
                gp[d1 * 512 + d2] = acc[mt][nt][r];
            }
        }
}

__global__ void gram_merge_kernel(const float* __restrict__ Gpart,
                                  float* __restrict__ G) {
    const int idx = blockIdx.x * 256 + threadIdx.x;   // 1024 blocks
    float s = 0.f;
    for (int b = 0; b < 32; ++b) s += Gpart[(size_t)b * 512 * 512 + idx];
    G[idx] = s;
}

// ---- per-row closed-form stats -> alpha, shift ---------------------------

__launch_bounds__(256)
__global__ void gu_kernel(const unsigned short* __restrict__ Abf,
                          const float* __restrict__ G,
                          const float* __restrict__ Svec,
                          const float* __restrict__ Tvec,
                          const double* __restrict__ E12,
                          const float* __restrict__ cvec,
                          const float* __restrict__ posv,
                          const int* __restrict__ pairs,
                          float* __restrict__ alpha_v,
                          float* __restrict__ shift_v) {
    __shared__ float u[8][512];
    __shared__ float red[8][3][4];
    const int t = threadIdx.x;
    const int lane = t & 63, wave = t >> 6;
    const int r0 = blockIdx.x * 8;
    #pragma unroll
    for (int p = 0; p < 8; ++p) {
        unsigned pk = *(const unsigned*)(Abf + (size_t)(r0 + p) * DIM + 2 * t);
        u[p][2 * t]     = bf2f((unsigned short)(pk & 0xffffu));
        u[p][2 * t + 1] = bf2f((unsigned short)(pk >> 16));
    }
    __syncthreads();
    float acc0[8], acc1[8];
    #pragma unroll
    for (int p = 0; p < 8; ++p) { acc0[p] = 0.f; acc1[p] = 0.f; }
    for (int d1 = 0; d1 < 512; ++d1) {
        const float2 g = *(const float2*)(G + d1 * 512 + 2 * t);
        #pragma unroll
        for (int p = 0; p < 8; ++p) {
            const float up = u[p][d1];
            acc0[p] += up * g.x;
            acc1[p] += up * g.y;
        }
    }
    const float sv0 = Svec[2 * t], sv1 = Svec[2 * t + 1];
    const float tv0 = Tvec[2 * t], tv1 = Tvec[2 * t + 1];
    #pragma unroll
    for (int p = 0; p < 8; ++p) {
        const float u0 = u[p][2 * t], u1 = u[p][2 * t + 1];
        float pdS = u0 * sv0 + u1 * sv1;
        float pdT = u0 * tv0 + u1 * tv1;
        float pq  = u0 * acc0[p] + u1 * acc1[p];
        #pragma unroll
        for (int off = 1; off < 64; off <<= 1) {
            pdS += __shfl_xor(pdS, off);
            pdT += __shfl_xor(pdT, off);
            pq  += __shfl_xor(pq,  off);
        }
        if (lane == 0) {
            red[p][0][wave] = pdS;
            red[p][1][wave] = pdT;
            red[p][2][wave] = pq;
        }
    }
    __syncthreads();
    if (t < 8) {
        const int p = t;
        const double dS = (double)red[p][0][0] + red[p][0][1] + red[p][0][2] + red[p][0][3];
        const double dT = (double)red[p][1][0] + red[p][1][1] + red[p][1][2] + red[p][1][3];
        const double qq = (double)red[p][2][0] + red[p][2][1] + red[p][2][2] + red[p][2][3];
        const int row = r0 + p;
        const int pp  = row & (NPAIR - 1);
        const double c  = (double)cvec[row];
        const double E1 = E12[0], E2 = E12[1];
        const double N  = (double)NODES;
        double Sx  = N * c + 2.0 * dS - E1;
        double Sxx = (N * c * c - 2.0 * c * E1 + E2) + 4.0 * (c * dS - dT) + 4.0 * qq;
        const int li = pairs[2 * pp], ri = pairs[2 * pp + 1];
        const double pos = (double)posv[pp];
        if (li != ri) {
            const double x1 = pos + (double)GAMMA_F, x2 = (double)GAMMA_F;
            Sx  -= x1 + x2;
            Sxx -= x1 * x1 + x2 * x2;
        } else {
            Sx -= 2.0 * (double)GAMMA_F;   // value flips sign; square unchanged
        }
        const double mu  = Sx / N;
        const double var = Sxx / N - mu * mu;
        const double sd  = sqrt(fmax(var, 1e-30));
        const double al  = (double)LAMB_F / sd;
        alpha_v[row] = (float)al;
        shift_v[row] = (float)(al * mu + (double)SHIFT_F);
    }
}

// ---- the big GEMM (R0-verbatim, green 3x) + shifted-exp epilogue ---------

__launch_bounds__(256, 2)
__global__ void gemm_kernel(const unsigned short* __restrict__ Abf,
                            const unsigned short* __restrict__ Ebf,
                            const float* __restrict__ cvec,
                            const float* __restrict__ esq,
                            const int*   __restrict__ pairs,
                            const float* __restrict__ alpha_v,
                            const float* __restrict__ shift_v,
                            float* __restrict__ psum) {
    __shared__ unsigned short ldsA[TM * BK];  // 16 KB
    __shared__ unsigned short ldsB[TN * BK];  // 16 KB
    __shared__ float red_s[2][TM];
    __shared__ float alsh[TM], csh[TM], cmsh[TM];
    __shared__ int   lish[TM], rish[TM];

    const int tid  = threadIdx.x;
    const int lane = tid & 63;
    const int wave = tid >> 6;
    const int wx = wave & 1;
    const int wy = wave >> 1;
    const int nb = blockIdx.x;
    const int n0 = nb * TN;
    const int m0 = blockIdx.y * TM;

    if (tid < TM) {
        const int gm = m0 + tid;
        alsh[tid] = alpha_v[gm];
        csh[tid]  = shift_v[gm];
        cmsh[tid] = cvec[gm];
        const int p = gm & (NPAIR - 1);
        lish[tid] = pairs[2 * p];
        rish[tid] = pairs[2 * p + 1];
    }

    f32x4 zero4 = {0.f, 0.f, 0.f, 0.f};
    f32x4 acc[4][4];
    #pragma unroll
    for (int i = 0; i < 4; ++i)
        #pragma unroll
        for (int j = 0; j < 4; ++j) acc[i][j] = zero4;

    const int lrow   = lane >> 3;
    const int lchunk = lane & 7;
    const int r15 = lane & 15;
    const int q   = lane >> 4;

    for (int kt = 0; kt < DIM / BK; ++kt) {
        const int kb = kt * BK;
        #pragma unroll
        for (int j = 0; j < 4; ++j) {
            const int rbase = (wave * 4 + j) * 8;
            const int row   = rbase + lrow;
            const int gch   = lchunk ^ (row & 7);
            gload_lds16(Abf + ((size_t)(m0 + row) * DIM + kb + gch * 8), &ldsA[rbase * BK]);
            gload_lds16(Ebf + ((size_t)(n0 + row) * DIM + kb + gch * 8), &ldsB[rbase * BK]);
        }
        __builtin_amdgcn_s_waitcnt(0);
        __syncthreads();
        #pragma unroll
        for (int h = 0; h < 2; ++h) {
            short8 af[4], bfr[4];
            #pragma unroll
            for (int mt = 0; mt < 4; ++mt) {
                int row = wy * 64 + mt * 16 + r15;
                int c   = (h * 4 + q) ^ (row & 7);
                af[mt] = *(const short8*)&ldsA[row * BK + c * 8];
            }
            #pragma unroll
            for (int nt = 0; nt < 4; ++nt) {
                int row = wx * 64 + nt * 16 + r15;
                int c   = (h * 4 + q) ^ (row & 7);
                bfr[nt] = *(const short8*)&ldsB[row * BK + c * 8];
            }
            #pragma unroll
            for (int mt = 0; mt < 4; ++mt)
                #pragma unroll
                for (int nt = 0; nt < 4; ++nt)
                    acc[mt][nt] = __builtin_amdgcn_mfma_f32_16x16x32_bf16(
                        af[mt], bfr[nt], acc[mt][nt], 0, 0, 0);
        }
        __syncthreads();
    }

    // epilogue: se = sum exp(al*x - C); C absorbs mu and 7-sigma headroom
    #pragma unroll
    for (int mt = 0; mt < 4; ++mt) {
        #pragma unroll
        for (int r = 0; r < 4; ++r) {
            const int rit = wy * 64 + mt * 16 + q * 4 + r;
            const float cm = cmsh[rit];
            const float al = alsh[rit];
            const float Cc = csh[rit];
            const int li = lish[rit], ri = rish[rit];
            float se = 0.f;
            #pragma unroll
            for (int nt = 0; nt < 4; ++nt) {
                const int gn = n0 + wx * 64 + nt * 16 + r15;
                float xv = cm + 2.0f * acc[mt][nt][r] - esq[gn];
                float msk = 1.0f - (float)(gn == li) - (float)(gn == ri);
                xv *= msk;
                float term = __expf(fmaf(al, xv, -Cc));
                se += (gn < NODES) ? term : 0.f;
            }
            #pragma unroll
            for (int o = 1; o < 16; o <<= 1) se += __shfl_xor(se, o);
            if (r15 == 0) red_s[wx][rit] = se;
        }
    }
    __syncthreads();
    if (tid < TM) {
        psum[(size_t)nb * MROWS + m0 + tid] = red_s[0][tid] + red_s[1][tid];
    }
}

// ---- fused partial-sum + loss, then mean ---------------------------------

__global__ void lse_loss_kernel(const float* __restrict__ psum,
                                float* __restrict__ loss_v) {
    const int row = blockIdx.x * 256 + threadIdx.x;   // 16 blocks
    float s = 0.f;
    for (int nb = 0; nb < NB; ++nb)
        s += psum[(size_t)nb * MROWS + row];
    loss_v[row] = (TAU_F + SHIFT_F) + logf(s);
}

__global__ void final_kernel(const float* __restrict__ loss_v,
                             float* __restrict__ out) {
    __shared__ double wpart[4];
    int t = threadIdx.x;
    double s = 0.0;
    for (int i = t; i < MROWS; i += 256)
        s += (double)loss_v[i];
    #pragma unroll
    for (int off = 1; off < 64; off <<= 1) s += __shfl_xor(s, off);
    if ((t & 63) == 0) wpart[t >> 6] = s;
    __syncthreads();
    if (t == 0) out[0] = (float)((wpart[0] + wpart[1] + wpart[2] + wpart[3]) / (double)NPAIR);
}

// ---- host ----------------------------------------------------------------

extern "C" void kernel_launch(void* const* d_in, const int* in_sizes, int n_in,
                              void* d_out, int out_size, void* d_ws, size_t ws_size,
                              hipStream_t stream) {
    const int*   pairs = (const int*)d_in[0];
    const float* emb   = (const float*)d_in[1];
    float* out = (float*)d_out;

    char* ws = (char*)d_ws;
    size_t off = 0;
    auto alloc = [&](size_t bytes) -> void* {
        void* p = ws + off;
        off += (bytes + 255) & ~(size_t)255;
        return p;
    };
    unsigned short* Ebf = (unsigned short*)alloc((size_t)NPAD * DIM * 2);
    unsigned short* Abf = (unsigned short*)alloc((size_t)MROWS * DIM * 2);
    float*  esq     = (float*)alloc((size_t)NPAD * 4);
    float*  cvec    = (float*)alloc((size_t)MROWS * 4);
    float*  posv    = (float*)alloc((size_t)NPAIR * 4);
    float*  Spart   = (float*)alloc((size_t)512 * DIM * 4);
    float*  Tpart   = (float*)alloc((size_t)512 * DIM * 4);
    float*  E1part  = (float*)alloc((size_t)512 * 4);
    float*  E2part  = (float*)alloc((size_t)512 * 4);
    float*  Svec    = (float*)alloc((size_t)DIM * 4);
    float*  Tvec    = (float*)alloc((size_t)DIM * 4);
    double* E12     = (double*)alloc(2 * sizeof(double));
    float*  G       = (float*)alloc((size_t)512 * 512 * 4);
    float*  alpha_v = (float*)alloc((size_t)MROWS * 4);
    float*  shift_v = (float*)alloc((size_t)MROWS * 4);
    float*  loss_v  = (float*)alloc((size_t)MROWS * 4);
    // union region: Gram partials (32 MB), then psum (12.8 MB) after merge
    char* uni = (char*)alloc((size_t)32 * 512 * 512 * 4);
    float* Gpart = (float*)uni;
    float* psum  = (float*)uni;
    if (off > ws_size) return;  // workspace too small — fail visibly

    convert_stats_kernel<<<512, 256, 0, stream>>>(emb, Ebf, esq,
                                                  Spart, Tpart, E1part, E2part);
    stats_merge_kernel<<<34, 256, 0, stream>>>(Spart, Tpart, E1part, E2part,
                                               Svec, Tvec, E12);
    gather_kernel<<<NPAIR, 64, 0, stream>>>(pairs, emb, Abf, cvec, posv);

    gram_kernel<<<dim3(4, 4, 32), 256, 0, stream>>>(Ebf, Gpart);
    gram_merge_kernel<<<1024, 256, 0, stream>>>(Gpart, G);
    gu_kernel<<<MROWS / 8, 256, 0, stream>>>(Abf, G, Svec, Tvec, E12,
                                             cvec, posv, pairs, alpha_v, shift_v);

    gemm_kernel<<<dim3(NB, MPAGES), 256, 0, stream>>>(Abf, Ebf, cvec, esq, pairs,
                                                      alpha_v, shift_v, psum);
    lse_loss_kernel<<<16, 256, 0, stream>>>(psum, loss_v);
    final_kernel<<<1, 256, 0, stream>>>(loss_v, out);
}